// Round 8
// baseline (726.396 us; speedup 1.0000x reference)
//
#include <hip/hip_runtime.h>
#include <hip/hip_bf16.h>

// PhraseDecoderLayer: B=4,S=1024,D=1024,H=16,HD=64,DFF=4096,MEM=256.
// Round 8: gemm128 restructured — B-fragments load DIRECT global->VGPR
// (register double-buffered, one K-step of latency cover, zero barrier
// coupling); A keeps depth-2 LDS pipeline (LDS halved to 10KB); supertile
// grid swizzle for L2 locality. Attention / kv GEMMs / LN / canon unchanged.

using bf16 = __hip_bfloat16;
typedef __bf16 bf16x8 __attribute__((ext_vector_type(8)));
typedef float f32x4 __attribute__((ext_vector_type(4)));

static constexpr int Bn = 4, Ssz = 1024, Dm = 1024, Hh = 16, HDd = 64, DFFn = 4096, MEMn = 256;

__device__ inline float bf2f(bf16 x) { return __bfloat162float(x); }
__device__ inline bf16 f2bf(float x) { return __float2bfloat16(x); }

// ---------------- dtype detect ----------------
__global__ void detect_kernel(const unsigned* __restrict__ cosw, int* __restrict__ flag) {
  if (threadIdx.x == 0) *flag = (cosw[0] == 0x3F800000u) ? 1 : 0;
}

// ---------------- fused canonicalize: all inputs -> bf16 (+f32 resid for seg0) ----
struct CanonArgs {
  const void* src[23];
  void* dst[23];
  int n[23];  // element count (0 = skip); all counts divisible by 4
};
__global__ __launch_bounds__(256) void canon_all(CanonArgs a, float* __restrict__ resid,
                                                 const int* __restrict__ flagp) {
  const int seg = blockIdx.y;
  const int n4 = a.n[seg] >> 2;
  if (n4 == 0) return;
  const int fl = *flagp;  // wave-uniform
  if (fl) {
    const float4* s = (const float4*)a.src[seg];
    bf16* d = (bf16*)a.dst[seg];
    for (int i = blockIdx.x * 256 + threadIdx.x; i < n4; i += gridDim.x * 256) {
      float4 v = s[i];
      bf16 t[4] = {f2bf(v.x), f2bf(v.y), f2bf(v.z), f2bf(v.w)};
      *reinterpret_cast<unsigned long long*>(d + i * 4) =
          *reinterpret_cast<unsigned long long*>(t);
      if (seg == 0) *reinterpret_cast<float4*>(resid + i * 4) = v;
    }
  } else {
    const unsigned long long* s = (const unsigned long long*)a.src[seg];
    unsigned long long* d = (unsigned long long*)a.dst[seg];
    for (int i = blockIdx.x * 256 + threadIdx.x; i < n4; i += gridDim.x * 256) {
      unsigned long long v = s[i];
      d[i] = v;
      if (seg == 0) {
        const unsigned short* u = reinterpret_cast<const unsigned short*>(&v);
        float4 f;
        f.x = __uint_as_float(((unsigned)u[0]) << 16);
        f.y = __uint_as_float(((unsigned)u[1]) << 16);
        f.z = __uint_as_float(((unsigned)u[2]) << 16);
        f.w = __uint_as_float(((unsigned)u[3]) << 16);
        *reinterpret_cast<float4*>(resid + i * 4) = f;
      }
    }
  }
}

// ---------------- LayerNorm (rows of 1024, fp32 in, bf16 out) ----------------
__global__ __launch_bounds__(256) void ln_kernel(const float* __restrict__ x,
                                                 const bf16* __restrict__ g,
                                                 const bf16* __restrict__ bb,
                                                 bf16* __restrict__ y) {
  const int row = blockIdx.x;
  const float* xr = x + (size_t)row * Dm;
  const int i0 = threadIdx.x * 4;
  float4 v = *reinterpret_cast<const float4*>(xr + i0);
  float s = v.x + v.y + v.z + v.w;
  float ss = v.x * v.x + v.y * v.y + v.z * v.z + v.w * v.w;
#pragma unroll
  for (int o = 32; o > 0; o >>= 1) {
    s += __shfl_down(s, o);
    ss += __shfl_down(ss, o);
  }
  __shared__ float shs[4], shss[4];
  const int wave = threadIdx.x >> 6, lane = threadIdx.x & 63;
  if (lane == 0) { shs[wave] = s; shss[wave] = ss; }
  __syncthreads();
  s = shs[0] + shs[1] + shs[2] + shs[3];
  ss = shss[0] + shss[1] + shss[2] + shss[3];
  const float mu = s * (1.0f / Dm);
  const float var = fmaxf(ss * (1.0f / Dm) - mu * mu, 0.0f);
  const float rs = rsqrtf(var + 1e-5f);
  bf16* yr = y + (size_t)row * Dm + i0;
  float vv[4] = {v.x, v.y, v.z, v.w};
#pragma unroll
  for (int j = 0; j < 4; ++j)
    yr[j] = f2bf((vv[j] - mu) * rs * bf2f(g[i0 + j]) + bf2f(bb[i0 + j]));
}

// ---------------- GEMM 64x64 (round-2 verified; used for M=1024 kv) --------
__global__ __launch_bounds__(256) void gemm_bt(
    const bf16* __restrict__ A, const bf16* __restrict__ W,
    const bf16* __restrict__ bias, bf16* __restrict__ outB, float* __restrict__ outF,
    const float* __restrict__ residIn, float* __restrict__ residOut,
    const int* __restrict__ flagp, int M, int N, int K, int epi) {
  __shared__ bf16 As[64][40];
  __shared__ bf16 Ws[64][40];
  const int tid = threadIdx.x;
  const int m0 = blockIdx.x * 64, n0 = blockIdx.y * 64;
  const int wave = tid >> 6, lane = tid & 63;
  const int wm = wave >> 1, wn = wave & 1;
  const int quad = lane >> 4, m16 = lane & 15;
  const int lr = tid >> 2, lc = (tid & 3) * 8;

  f32x4 acc[2][2] = {};

  const bf16* Ap = A + (size_t)(m0 + lr) * K + lc;
  const bf16* Wp = W + (size_t)(n0 + lr) * K + lc;
  for (int k0 = 0; k0 < K; k0 += 32) {
    float4 av = *reinterpret_cast<const float4*>(Ap + k0);
    float4 wv = *reinterpret_cast<const float4*>(Wp + k0);
    *reinterpret_cast<float4*>(&As[lr][lc]) = av;
    *reinterpret_cast<float4*>(&Ws[lr][lc]) = wv;
    __syncthreads();
    bf16x8 aF[2], bF[2];
#pragma unroll
    for (int t = 0; t < 2; ++t) {
      aF[t] = *reinterpret_cast<const bf16x8*>(&As[wm * 32 + t * 16 + m16][quad * 8]);
      bF[t] = *reinterpret_cast<const bf16x8*>(&Ws[wn * 32 + t * 16 + m16][quad * 8]);
    }
#pragma unroll
    for (int mt = 0; mt < 2; ++mt)
#pragma unroll
      for (int nt = 0; nt < 2; ++nt)
        acc[mt][nt] = __builtin_amdgcn_mfma_f32_16x16x32_bf16(aF[mt], bF[nt], acc[mt][nt], 0, 0, 0);
    __syncthreads();
  }
  const int fl = (epi == 3) ? *flagp : 0;
#pragma unroll
  for (int mt = 0; mt < 2; ++mt) {
#pragma unroll
    for (int nt = 0; nt < 2; ++nt) {
      const int col = n0 + wn * 32 + nt * 16 + m16;
      const float bv = bf2f(bias[col]);
#pragma unroll
      for (int r = 0; r < 4; ++r) {
        const int row = m0 + wm * 32 + mt * 16 + quad * 4 + r;
        const size_t idx = (size_t)row * N + col;
        float v = acc[mt][nt][r] + bv;
        if (epi == 0) {
          outB[idx] = f2bf(v);
        } else if (epi == 1) {
          outB[idx] = f2bf(0.5f * v * (1.0f + erff(v * 0.70710678118654752f)));
        } else if (epi == 2) {
          residOut[idx] = residIn[idx] + v;
        } else {
          const float rr = residIn[idx] + v;
          if (fl) outF[idx] = rr; else outB[idx] = f2bf(rr);
        }
      }
    }
  }
}

// ---------------- GEMM 128x128: A via depth-2 LDS, B direct global->VGPR ----
// B-frag global layout == its MFMA operand layout: row n0+wn*64+t*16+m16,
// cols k..k+7 (16 rows x 64B per wave-load — L2-friendly, W bands stay hot).
// b0/b1 register double-buffer: frags for tile s+1 load during tile s.
// Supertile swizzle: groups of 8 n-tiles per m-band for L2 locality.
__global__ __launch_bounds__(256) void gemm128(
    const bf16* __restrict__ A, const bf16* __restrict__ W,
    const bf16* __restrict__ bias, bf16* __restrict__ outB, float* __restrict__ outF,
    const float* __restrict__ residIn, float* __restrict__ residOut,
    const int* __restrict__ flagp, int M, int N, int K, int epi) {
  __shared__ bf16 As[128][40];
  const int tid = threadIdx.x;
  const int wave = tid >> 6, lane = tid & 63;
  const int wm = wave >> 1, wn = wave & 1;
  const int quad = lane >> 4, m16 = lane & 15;

  // supertile swizzle (gridDim.y is always a multiple of 8 here)
  const int numM = gridDim.x;
  const int lin = blockIdx.y * numM + blockIdx.x;
  const int grpSz = numM * 8;
  const int gid = lin / grpSz;
  const int rem = lin - gid * grpSz;
  const int m0 = (rem >> 3) * 128;
  const int n0 = (gid * 8 + (rem & 7)) * 128;

  const int lr = tid >> 2;         // 0..63
  const int lc = (tid & 3) * 8;    // 0,8,16,24
  const bf16* Ap = A + (size_t)(m0 + lr) * K + lc;
  const size_t rowOff = (size_t)64 * K;
  // per-lane B row pointer (frag t at +t*16*K)
  const bf16* Wr = W + (size_t)(n0 + wn * 64 + m16) * K + quad * 8;
  const size_t wK = (size_t)K;

  f32x4 acc[4][4] = {};
  bf16x8 b0[4], b1[4];

  // prologue: A tiles 0 (X) and 1 (Y) into regs; B frags for tile 0 into b0
  float4 ax0 = *reinterpret_cast<const float4*>(Ap);
  float4 ax1 = *reinterpret_cast<const float4*>(Ap + rowOff);
  float4 ay0 = *reinterpret_cast<const float4*>(Ap + 32);
  float4 ay1 = *reinterpret_cast<const float4*>(Ap + rowOff + 32);
#pragma unroll
  for (int t = 0; t < 4; ++t)
    b0[t] = *reinterpret_cast<const bf16x8*>(Wr + (size_t)t * 16 * wK);

  const int nsteps = K >> 5;  // K % 64 == 0 always -> nsteps even
  for (int s = 0; s < nsteps; s += 2) {
    // ---- sub-step A: tile s (A stage X, B regs b0) ----
    *reinterpret_cast<float4*>(&As[lr][lc]) = ax0;
    *reinterpret_cast<float4*>(&As[64 + lr][lc]) = ax1;
    __syncthreads();
    if (s + 2 < nsteps) {
      const int k2 = (s + 2) * 32;
      ax0 = *reinterpret_cast<const float4*>(Ap + k2);
      ax1 = *reinterpret_cast<const float4*>(Ap + rowOff + k2);
    }
    {
      const int k1 = (s + 1) * 32;  // tile s+1 always exists in-loop
#pragma unroll
      for (int t = 0; t < 4; ++t)
        b1[t] = *reinterpret_cast<const bf16x8*>(Wr + (size_t)t * 16 * wK + k1);
    }
    {
      bf16x8 aF[4];
#pragma unroll
      for (int t = 0; t < 4; ++t)
        aF[t] = *reinterpret_cast<const bf16x8*>(&As[wm * 64 + t * 16 + m16][quad * 8]);
#pragma unroll
      for (int mt = 0; mt < 4; ++mt)
#pragma unroll
        for (int nt = 0; nt < 4; ++nt)
          acc[mt][nt] = __builtin_amdgcn_mfma_f32_16x16x32_bf16(aF[mt], b0[nt], acc[mt][nt], 0, 0, 0);
    }
    __syncthreads();
    // ---- sub-step B: tile s+1 (A stage Y, B regs b1) ----
    *reinterpret_cast<float4*>(&As[lr][lc]) = ay0;
    *reinterpret_cast<float4*>(&As[64 + lr][lc]) = ay1;
    __syncthreads();
    if (s + 3 < nsteps) {
      const int k3 = (s + 3) * 32;
      ay0 = *reinterpret_cast<const float4*>(Ap + k3);
      ay1 = *reinterpret_cast<const float4*>(Ap + rowOff + k3);
    }
    if (s + 2 < nsteps) {
      const int k2 = (s + 2) * 32;
#pragma unroll
      for (int t = 0; t < 4; ++t)
        b0[t] = *reinterpret_cast<const bf16x8*>(Wr + (size_t)t * 16 * wK + k2);
    }
    {
      bf16x8 aF[4];
#pragma unroll
      for (int t = 0; t < 4; ++t)
        aF[t] = *reinterpret_cast<const bf16x8*>(&As[wm * 64 + t * 16 + m16][quad * 8]);
#pragma unroll
      for (int mt = 0; mt < 4; ++mt)
#pragma unroll
        for (int nt = 0; nt < 4; ++nt)
          acc[mt][nt] = __builtin_amdgcn_mfma_f32_16x16x32_bf16(aF[mt], b1[nt], acc[mt][nt], 0, 0, 0);
    }
    __syncthreads();
  }
  const int fl = (epi == 3) ? *flagp : 0;
  // C/D layout: col = lane&15, row = quad*4 + reg
#pragma unroll
  for (int mt = 0; mt < 4; ++mt) {
#pragma unroll
    for (int nt = 0; nt < 4; ++nt) {
      const int col = n0 + wn * 64 + nt * 16 + m16;
      const float bv = bf2f(bias[col]);
#pragma unroll
      for (int r = 0; r < 4; ++r) {
        const int row = m0 + wm * 64 + mt * 16 + quad * 4 + r;
        const size_t idx = (size_t)row * N + col;
        float v = acc[mt][nt][r] + bv;
        if (epi == 0) {
          outB[idx] = f2bf(v);
        } else if (epi == 1) {
          outB[idx] = f2bf(0.5f * v * (1.0f + erff(v * 0.70710678118654752f)));
        } else if (epi == 2) {
          residOut[idx] = residIn[idx] + v;
        } else {
          const float rr = residIn[idx] + v;
          if (fl) outF[idx] = rr; else outB[idx] = f2bf(rr);
        }
      }
    }
  }
}

// ---------------- RoPE in-place on qkv buffer [4096, 3072] ----------------
__global__ __launch_bounds__(256) void rope_kernel(bf16* __restrict__ qkv,
                                                   const bf16* __restrict__ cosb,
                                                   const bf16* __restrict__ sinb) {
  const int idx = blockIdx.x * 256 + threadIdx.x;  // over 4096*16*32
  const int i = idx & 31;
  const int h = (idx >> 5) & 15;
  const int r = idx >> 9;
  const int s = r & (Ssz - 1);
  const float c = bf2f(cosb[s * 32 + i]);
  const float sn = bf2f(sinb[s * 32 + i]);
  bf16* base = qkv + (size_t)r * (3 * Dm) + h * 64 + 2 * i;
  float x0 = bf2f(base[0]), x1 = bf2f(base[1]);
  base[0] = f2bf(x0 * c - x1 * sn);
  base[1] = f2bf(x0 * sn + x1 * c);
  x0 = bf2f(base[Dm]); x1 = bf2f(base[Dm + 1]);
  base[Dm] = f2bf(x0 * c - x1 * sn);
  base[Dm + 1] = f2bf(x0 * sn + x1 * c);
}

// ---------------- MFMA flash attention (round-3 verified) ----------------
__global__ __launch_bounds__(256) void attn_mfma(
    const bf16* __restrict__ Qb, const bf16* __restrict__ Kb, const bf16* __restrict__ Vb,
    bf16* __restrict__ Ob, int qStride, int kvStride, int kvLen, int causal, float scale) {
  __shared__ bf16 Ks[64][72];
  __shared__ bf16 Vt[64][72];
  __shared__ bf16 Ps[64][72];
  const int tid = threadIdx.x;
  const int wave = tid >> 6, lane = tid & 63;
  const int quad = lane >> 4, m16 = lane & 15;
  const int b = blockIdx.z, h = blockIdx.y;
  const int q0 = blockIdx.x * 64;
  const int sr = tid >> 2, sc = (tid & 3) * 16;

  {
    const bf16* qp = Qb + (size_t)(b * Ssz + q0 + sr) * qStride + h * 64 + sc;
    float4 a = reinterpret_cast<const float4*>(qp)[0];
    float4 bb2 = reinterpret_cast<const float4*>(qp)[1];
    *reinterpret_cast<float4*>(&Ps[sr][sc]) = a;
    *reinterpret_cast<float4*>(&Ps[sr][sc + 8]) = bb2;
  }
  __syncthreads();
  bf16x8 qf[2];
  qf[0] = *reinterpret_cast<const bf16x8*>(&Ps[wave * 16 + m16][quad * 8]);
  qf[1] = *reinterpret_cast<const bf16x8*>(&Ps[wave * 16 + m16][32 + quad * 8]);

  f32x4 oacc[4] = {};
  float mrow[4], lrow[4];
#pragma unroll
  for (int r = 0; r < 4; ++r) { mrow[r] = -30000.0f; lrow[r] = 0.0f; }

  const int nk = causal ? (q0 + 64) : kvLen;
  for (int kt = 0; kt < nk; kt += 64) {
    {
      const bf16* kp = Kb + (size_t)(b * kvLen + kt + sr) * kvStride + h * 64 + sc;
      float4 k1 = reinterpret_cast<const float4*>(kp)[0];
      float4 k2 = reinterpret_cast<const float4*>(kp)[1];
      *reinterpret_cast<float4*>(&Ks[sr][sc]) = k1;
      *reinterpret_cast<float4*>(&Ks[sr][sc + 8]) = k2;
      const bf16* vp = Vb + (size_t)(b * kvLen + kt + sr) * kvStride + h * 64 + sc;
      float4 v1 = reinterpret_cast<const float4*>(vp)[0];
      float4 v2 = reinterpret_cast<const float4*>(vp)[1];
      const bf16* tv1 = reinterpret_cast<const bf16*>(&v1);
      const bf16* tv2 = reinterpret_cast<const bf16*>(&v2);
#pragma unroll
      for (int j = 0; j < 8; ++j) {
        Vt[sc + j][sr] = tv1[j];
        Vt[sc + 8 + j][sr] = tv2[j];
      }
    }
    __syncthreads();

    f32x4 sacc[4] = {};
#pragma unroll
    for (int nt = 0; nt < 4; ++nt) {
      bf16x8 kf0 = *reinterpret_cast<const bf16x8*>(&Ks[nt * 16 + m16][quad * 8]);
      bf16x8 kf1 = *reinterpret_cast<const bf16x8*>(&Ks[nt * 16 + m16][32 + quad * 8]);
      sacc[nt] = __builtin_amdgcn_mfma_f32_16x16x32_bf16(qf[0], kf0, sacc[nt], 0, 0, 0);
      sacc[nt] = __builtin_amdgcn_mfma_f32_16x16x32_bf16(qf[1], kf1, sacc[nt], 0, 0, 0);
    }
    const bool dmask = (causal != 0) && (kt == q0);
#pragma unroll
    for (int nt = 0; nt < 4; ++nt) {
#pragma unroll
      for (int r = 0; r < 4; ++r) {
        float s = sacc[nt][r] * scale;
        if (dmask && (nt * 16 + m16 > wave * 16 + quad * 4 + r)) s = -30000.0f;
        sacc[nt][r] = s;
      }
    }

#pragma unroll
    for (int r = 0; r < 4; ++r) {
      float mx = fmaxf(fmaxf(sacc[0][r], sacc[1][r]), fmaxf(sacc[2][r], sacc[3][r]));
#pragma unroll
      for (int off = 1; off < 16; off <<= 1) mx = fmaxf(mx, __shfl_xor(mx, off));
      const float mn = fmaxf(mrow[r], mx);
      const float corr = __expf(mrow[r] - mn);
      mrow[r] = mn;
      float psum = 0.0f;
#pragma unroll
      for (int nt = 0; nt < 4; ++nt) {
        const float p = __expf(sacc[nt][r] - mn);
        sacc[nt][r] = p;
        psum += p;
      }
#pragma unroll
      for (int off = 1; off < 16; off <<= 1) psum += __shfl_xor(psum, off);
      lrow[r] = lrow[r] * corr + psum;
#pragma unroll
      for (int nt = 0; nt < 4; ++nt) oacc[nt][r] *= corr;
#pragma unroll
      for (int nt = 0; nt < 4; ++nt)
        Ps[wave * 16 + quad * 4 + r][nt * 16 + m16] = f2bf(sacc[nt][r]);
    }
    bf16x8 pf0 = *reinterpret_cast<const bf16x8*>(&Ps[wave * 16 + m16][quad * 8]);
    bf16x8 pf1 = *reinterpret_cast<const bf16x8*>(&Ps[wave * 16 + m16][32 + quad * 8]);
#pragma unroll
    for (int nt = 0; nt < 4; ++nt) {
      bf16x8 vf0 = *reinterpret_cast<const bf16x8*>(&Vt[nt * 16 + m16][quad * 8]);
      bf16x8 vf1 = *reinterpret_cast<const bf16x8*>(&Vt[nt * 16 + m16][32 + quad * 8]);
      oacc[nt] = __builtin_amdgcn_mfma_f32_16x16x32_bf16(pf0, vf0, oacc[nt], 0, 0, 0);
      oacc[nt] = __builtin_amdgcn_mfma_f32_16x16x32_bf16(pf1, vf1, oacc[nt], 0, 0, 0);
    }
    __syncthreads();
  }

  float inv[4];
#pragma unroll
  for (int r = 0; r < 4; ++r) inv[r] = 1.0f / lrow[r];
#pragma unroll
  for (int r = 0; r < 4; ++r) {
    bf16* op = Ob + (size_t)(b * Ssz + q0 + wave * 16 + quad * 4 + r) * Dm + h * 64 + m16;
#pragma unroll
    for (int nt = 0; nt < 4; ++nt) op[nt * 16] = f2bf(oacc[nt][r] * inv[r]);
  }
}

extern "C" void kernel_launch(void* const* d_in, const int* in_sizes, int n_in,
                              void* d_out, int out_size, void* d_ws, size_t ws_size,
                              hipStream_t stream) {
  char* ws = (char*)d_ws;
  int* flagp   = (int*)ws;                          // [0,1MB) control
  float* resid = (float*)(ws + (1ull << 20));       // 16MB fp32 residual
  bf16* xln    = (bf16*)(ws + (17ull << 20));       // 8MB LN output
  bf16* aout   = (bf16*)(ws + (25ull << 20));       // 8MB attn out
  bf16* big    = (bf16*)(ws + (33ull << 20));       // 32MB: qkv | qb | ffn1
  size_t off   = (65ull << 20);                     // canonical bf16 inputs

  detect_kernel<<<1, 64, 0, stream>>>((const unsigned*)d_in[3], flagp);

  CanonArgs ca;
  bf16* c[23];
  for (int i = 0; i < 23; ++i) {
    if (i == 2) { c[i] = nullptr; ca.src[i] = d_in[i]; ca.dst[i] = nullptr; ca.n[i] = 0; continue; }
    c[i] = (bf16*)(ws + off);
    const int n = in_sizes[i];
    off += ((size_t)n * 2 + 255) & ~(size_t)255;
    ca.src[i] = d_in[i];
    ca.dst[i] = c[i];
    ca.n[i] = n;
  }
  canon_all<<<dim3(256, 23), 256, 0, stream>>>(ca, resid, flagp);

  const bf16 *memory = c[1], *rope_cos = c[3], *rope_sin = c[4];
  const bf16 *qkv_w = c[5], *qkv_b = c[6], *out_w = c[7], *out_b = c[8];
  const bf16 *ca_in_w = c[9], *ca_in_b = c[10], *ca_out_w = c[11], *ca_out_b = c[12];
  const bf16 *ffn_w1 = c[13], *ffn_b1 = c[14], *ffn_w2 = c[15], *ffn_b2 = c[16];
  const bf16 *ln1_g = c[17], *ln1_b = c[18], *ln2_g = c[19], *ln2_b = c[20];
  const bf16 *ln3_g = c[21], *ln3_b = c[22];

  bf16* qb = big;
  bf16* kb = (bf16*)(ws + (41ull << 20));
  bf16* vb = (bf16*)(ws + (43ull << 20));
  bf16* outB = (bf16*)d_out;
  float* outF = (float*)d_out;

  const int ROWS = Bn * Ssz;   // 4096
  const float scale = 0.125f;  // 1/sqrt(64)

  // ---- self attention ----
  ln_kernel<<<ROWS, 256, 0, stream>>>(resid, ln1_g, ln1_b, xln);
  gemm128<<<dim3(ROWS / 128, (3 * Dm) / 128), 256, 0, stream>>>(
      xln, qkv_w, qkv_b, big, nullptr, nullptr, nullptr, nullptr, ROWS, 3 * Dm, Dm, 0);
  rope_kernel<<<(ROWS * Hh * (HDd / 2)) / 256, 256, 0, stream>>>(big, rope_cos, rope_sin);
  attn_mfma<<<dim3(Ssz / 64, Hh, Bn), 256, 0, stream>>>(
      big, big + Dm, big + 2 * Dm, aout, 3 * Dm, 3 * Dm, Ssz, 1, scale);
  gemm128<<<dim3(ROWS / 128, Dm / 128), 256, 0, stream>>>(
      aout, out_w, out_b, nullptr, nullptr, resid, resid, nullptr, ROWS, Dm, Dm, 2);

  // ---- cross attention ----
  ln_kernel<<<ROWS, 256, 0, stream>>>(resid, ln2_g, ln2_b, xln);
  gemm128<<<dim3(ROWS / 128, Dm / 128), 256, 0, stream>>>(
      xln, ca_in_w, ca_in_b, qb, nullptr, nullptr, nullptr, nullptr, ROWS, Dm, Dm, 0);
  gemm_bt<<<dim3((Bn * MEMn) / 64, Dm / 64), 256, 0, stream>>>(
      memory, ca_in_w + (size_t)Dm * Dm, ca_in_b + Dm, kb, nullptr, nullptr, nullptr, nullptr,
      Bn * MEMn, Dm, Dm, 0);
  gemm_bt<<<dim3((Bn * MEMn) / 64, Dm / 64), 256, 0, stream>>>(
      memory, ca_in_w + (size_t)2 * Dm * Dm, ca_in_b + 2 * Dm, vb, nullptr, nullptr, nullptr, nullptr,
      Bn * MEMn, Dm, Dm, 0);
  attn_mfma<<<dim3(Ssz / 64, Hh, Bn), 256, 0, stream>>>(
      qb, kb, vb, aout, Dm, Dm, MEMn, 0, scale);
  gemm128<<<dim3(ROWS / 128, Dm / 128), 256, 0, stream>>>(
      aout, ca_out_w, ca_out_b, nullptr, nullptr, resid, resid, nullptr, ROWS, Dm, Dm, 2);

  // ---- FFN ----
  ln_kernel<<<ROWS, 256, 0, stream>>>(resid, ln3_g, ln3_b, xln);
  gemm128<<<dim3(ROWS / 128, DFFn / 128), 256, 0, stream>>>(
      xln, ffn_w1, ffn_b1, big, nullptr, nullptr, nullptr, nullptr, ROWS, DFFn, Dm, 1);
  gemm128<<<dim3(ROWS / 128, Dm / 128), 256, 0, stream>>>(
      big, ffn_w2, ffn_b2, outB, outF, resid, nullptr, flagp, ROWS, Dm, DFFn, 3);
}

// Round 9
// 576.054 us; speedup vs baseline: 1.2610x; 1.2610x over previous
//
#include <hip/hip_runtime.h>
#include <hip/hip_bf16.h>

// PhraseDecoderLayer: B=4,S=1024,D=1024,H=16,HD=64,DFF=4096,MEM=256.
// Round 9: revert round-8's direct-global B (FETCH 41->144MB, L2 defeat).
// gemm128 = round-7 depth-2 register pipeline + LDS DOUBLE-BUFFER giving
// ONE barrier per K-step (skew argument: writer of buf[s&1] pre-barrier_s
// is separated from its previous readers by barrier_{s-1}).
// Attention / kv GEMMs / LN / canon unchanged from passing rounds.

using bf16 = __hip_bfloat16;
typedef __bf16 bf16x8 __attribute__((ext_vector_type(8)));
typedef float f32x4 __attribute__((ext_vector_type(4)));

static constexpr int Bn = 4, Ssz = 1024, Dm = 1024, Hh = 16, HDd = 64, DFFn = 4096, MEMn = 256;

__device__ inline float bf2f(bf16 x) { return __bfloat162float(x); }
__device__ inline bf16 f2bf(float x) { return __float2bfloat16(x); }

// ---------------- dtype detect ----------------
__global__ void detect_kernel(const unsigned* __restrict__ cosw, int* __restrict__ flag) {
  if (threadIdx.x == 0) *flag = (cosw[0] == 0x3F800000u) ? 1 : 0;
}

// ---------------- fused canonicalize: all inputs -> bf16 (+f32 resid for seg0) ----
struct CanonArgs {
  const void* src[23];
  void* dst[23];
  int n[23];  // element count (0 = skip); all counts divisible by 4
};
__global__ __launch_bounds__(256) void canon_all(CanonArgs a, float* __restrict__ resid,
                                                 const int* __restrict__ flagp) {
  const int seg = blockIdx.y;
  const int n4 = a.n[seg] >> 2;
  if (n4 == 0) return;
  const int fl = *flagp;  // wave-uniform
  if (fl) {
    const float4* s = (const float4*)a.src[seg];
    bf16* d = (bf16*)a.dst[seg];
    for (int i = blockIdx.x * 256 + threadIdx.x; i < n4; i += gridDim.x * 256) {
      float4 v = s[i];
      bf16 t[4] = {f2bf(v.x), f2bf(v.y), f2bf(v.z), f2bf(v.w)};
      *reinterpret_cast<unsigned long long*>(d + i * 4) =
          *reinterpret_cast<unsigned long long*>(t);
      if (seg == 0) *reinterpret_cast<float4*>(resid + i * 4) = v;
    }
  } else {
    const unsigned long long* s = (const unsigned long long*)a.src[seg];
    unsigned long long* d = (unsigned long long*)a.dst[seg];
    for (int i = blockIdx.x * 256 + threadIdx.x; i < n4; i += gridDim.x * 256) {
      unsigned long long v = s[i];
      d[i] = v;
      if (seg == 0) {
        const unsigned short* u = reinterpret_cast<const unsigned short*>(&v);
        float4 f;
        f.x = __uint_as_float(((unsigned)u[0]) << 16);
        f.y = __uint_as_float(((unsigned)u[1]) << 16);
        f.z = __uint_as_float(((unsigned)u[2]) << 16);
        f.w = __uint_as_float(((unsigned)u[3]) << 16);
        *reinterpret_cast<float4*>(resid + i * 4) = f;
      }
    }
  }
}

// ---------------- LayerNorm (rows of 1024, fp32 in, bf16 out) ----------------
__global__ __launch_bounds__(256) void ln_kernel(const float* __restrict__ x,
                                                 const bf16* __restrict__ g,
                                                 const bf16* __restrict__ bb,
                                                 bf16* __restrict__ y) {
  const int row = blockIdx.x;
  const float* xr = x + (size_t)row * Dm;
  const int i0 = threadIdx.x * 4;
  float4 v = *reinterpret_cast<const float4*>(xr + i0);
  float s = v.x + v.y + v.z + v.w;
  float ss = v.x * v.x + v.y * v.y + v.z * v.z + v.w * v.w;
#pragma unroll
  for (int o = 32; o > 0; o >>= 1) {
    s += __shfl_down(s, o);
    ss += __shfl_down(ss, o);
  }
  __shared__ float shs[4], shss[4];
  const int wave = threadIdx.x >> 6, lane = threadIdx.x & 63;
  if (lane == 0) { shs[wave] = s; shss[wave] = ss; }
  __syncthreads();
  s = shs[0] + shs[1] + shs[2] + shs[3];
  ss = shss[0] + shss[1] + shss[2] + shss[3];
  const float mu = s * (1.0f / Dm);
  const float var = fmaxf(ss * (1.0f / Dm) - mu * mu, 0.0f);
  const float rs = rsqrtf(var + 1e-5f);
  bf16* yr = y + (size_t)row * Dm + i0;
  float vv[4] = {v.x, v.y, v.z, v.w};
#pragma unroll
  for (int j = 0; j < 4; ++j)
    yr[j] = f2bf((vv[j] - mu) * rs * bf2f(g[i0 + j]) + bf2f(bb[i0 + j]));
}

// ---------------- GEMM 64x64 (round-2 verified; used for M=1024 kv) --------
__global__ __launch_bounds__(256) void gemm_bt(
    const bf16* __restrict__ A, const bf16* __restrict__ W,
    const bf16* __restrict__ bias, bf16* __restrict__ outB, float* __restrict__ outF,
    const float* __restrict__ residIn, float* __restrict__ residOut,
    const int* __restrict__ flagp, int M, int N, int K, int epi) {
  __shared__ bf16 As[64][40];
  __shared__ bf16 Ws[64][40];
  const int tid = threadIdx.x;
  const int m0 = blockIdx.x * 64, n0 = blockIdx.y * 64;
  const int wave = tid >> 6, lane = tid & 63;
  const int wm = wave >> 1, wn = wave & 1;
  const int quad = lane >> 4, m16 = lane & 15;
  const int lr = tid >> 2, lc = (tid & 3) * 8;

  f32x4 acc[2][2] = {};

  const bf16* Ap = A + (size_t)(m0 + lr) * K + lc;
  const bf16* Wp = W + (size_t)(n0 + lr) * K + lc;
  for (int k0 = 0; k0 < K; k0 += 32) {
    float4 av = *reinterpret_cast<const float4*>(Ap + k0);
    float4 wv = *reinterpret_cast<const float4*>(Wp + k0);
    *reinterpret_cast<float4*>(&As[lr][lc]) = av;
    *reinterpret_cast<float4*>(&Ws[lr][lc]) = wv;
    __syncthreads();
    bf16x8 aF[2], bF[2];
#pragma unroll
    for (int t = 0; t < 2; ++t) {
      aF[t] = *reinterpret_cast<const bf16x8*>(&As[wm * 32 + t * 16 + m16][quad * 8]);
      bF[t] = *reinterpret_cast<const bf16x8*>(&Ws[wn * 32 + t * 16 + m16][quad * 8]);
    }
#pragma unroll
    for (int mt = 0; mt < 2; ++mt)
#pragma unroll
      for (int nt = 0; nt < 2; ++nt)
        acc[mt][nt] = __builtin_amdgcn_mfma_f32_16x16x32_bf16(aF[mt], bF[nt], acc[mt][nt], 0, 0, 0);
    __syncthreads();
  }
  const int fl = (epi == 3) ? *flagp : 0;
#pragma unroll
  for (int mt = 0; mt < 2; ++mt) {
#pragma unroll
    for (int nt = 0; nt < 2; ++nt) {
      const int col = n0 + wn * 32 + nt * 16 + m16;
      const float bv = bf2f(bias[col]);
#pragma unroll
      for (int r = 0; r < 4; ++r) {
        const int row = m0 + wm * 32 + mt * 16 + quad * 4 + r;
        const size_t idx = (size_t)row * N + col;
        float v = acc[mt][nt][r] + bv;
        if (epi == 0) {
          outB[idx] = f2bf(v);
        } else if (epi == 1) {
          outB[idx] = f2bf(0.5f * v * (1.0f + erff(v * 0.70710678118654752f)));
        } else if (epi == 2) {
          residOut[idx] = residIn[idx] + v;
        } else {
          const float rr = residIn[idx] + v;
          if (fl) outF[idx] = rr; else outB[idx] = f2bf(rr);
        }
      }
    }
  }
}

// ---------------- GEMM 128x128: depth-2 reg pipeline + LDS dbuf, 1 barrier --
// X stage holds even tiles, Y odd. Step s: commit stage->buf[s&1] (pre-
// barrier), ONE __syncthreads, refill stage (tile s+2, 2-step cover, loads
// ride across 2 barriers in VGPRs), ds_read frags, 16 MFMA. Next write to
// buf[s&1] is at step s+2, separated from this step's readers by barrier s+1.
__global__ __launch_bounds__(256) void gemm128(
    const bf16* __restrict__ A, const bf16* __restrict__ W,
    const bf16* __restrict__ bias, bf16* __restrict__ outB, float* __restrict__ outF,
    const float* __restrict__ residIn, float* __restrict__ residOut,
    const int* __restrict__ flagp, int M, int N, int K, int epi) {
  __shared__ bf16 As[2][128][40];
  __shared__ bf16 Ws[2][128][40];
  const int tid = threadIdx.x;
  const int wave = tid >> 6, lane = tid & 63;
  const int wm = wave >> 1, wn = wave & 1;
  const int quad = lane >> 4, m16 = lane & 15;
  const int m0 = blockIdx.x * 128, n0 = blockIdx.y * 128;

  const int lr = tid >> 2;         // 0..63
  const int lc = (tid & 3) * 8;    // 0,8,16,24
  const bf16* Ap = A + (size_t)(m0 + lr) * K + lc;
  const bf16* Wp = W + (size_t)(n0 + lr) * K + lc;
  const size_t rowOff = (size_t)64 * K;

  f32x4 acc[4][4] = {};

  // prologue: tiles 0 (X) and 1 (Y) into registers
  float4 ax0 = *reinterpret_cast<const float4*>(Ap);
  float4 ax1 = *reinterpret_cast<const float4*>(Ap + rowOff);
  float4 wx0 = *reinterpret_cast<const float4*>(Wp);
  float4 wx1 = *reinterpret_cast<const float4*>(Wp + rowOff);
  float4 ay0 = *reinterpret_cast<const float4*>(Ap + 32);
  float4 ay1 = *reinterpret_cast<const float4*>(Ap + rowOff + 32);
  float4 wy0 = *reinterpret_cast<const float4*>(Wp + 32);
  float4 wy1 = *reinterpret_cast<const float4*>(Wp + rowOff + 32);

  const int nsteps = K >> 5;  // K % 64 == 0 -> nsteps even
  for (int s = 0; s < nsteps; s += 2) {
    // ---- step s (even tile, stage X -> buf0) ----
    *reinterpret_cast<float4*>(&As[0][lr][lc]) = ax0;
    *reinterpret_cast<float4*>(&As[0][64 + lr][lc]) = ax1;
    *reinterpret_cast<float4*>(&Ws[0][lr][lc]) = wx0;
    *reinterpret_cast<float4*>(&Ws[0][64 + lr][lc]) = wx1;
    __syncthreads();
    if (s + 2 < nsteps) {
      const int k2 = (s + 2) * 32;
      ax0 = *reinterpret_cast<const float4*>(Ap + k2);
      ax1 = *reinterpret_cast<const float4*>(Ap + rowOff + k2);
      wx0 = *reinterpret_cast<const float4*>(Wp + k2);
      wx1 = *reinterpret_cast<const float4*>(Wp + rowOff + k2);
    }
    {
      bf16x8 aF[4], bF[4];
#pragma unroll
      for (int t = 0; t < 4; ++t) {
        aF[t] = *reinterpret_cast<const bf16x8*>(&As[0][wm * 64 + t * 16 + m16][quad * 8]);
        bF[t] = *reinterpret_cast<const bf16x8*>(&Ws[0][wn * 64 + t * 16 + m16][quad * 8]);
      }
#pragma unroll
      for (int mt = 0; mt < 4; ++mt)
#pragma unroll
        for (int nt = 0; nt < 4; ++nt)
          acc[mt][nt] = __builtin_amdgcn_mfma_f32_16x16x32_bf16(aF[mt], bF[nt], acc[mt][nt], 0, 0, 0);
    }
    // ---- step s+1 (odd tile, stage Y -> buf1) ----
    *reinterpret_cast<float4*>(&As[1][lr][lc]) = ay0;
    *reinterpret_cast<float4*>(&As[1][64 + lr][lc]) = ay1;
    *reinterpret_cast<float4*>(&Ws[1][lr][lc]) = wy0;
    *reinterpret_cast<float4*>(&Ws[1][64 + lr][lc]) = wy1;
    __syncthreads();
    if (s + 3 < nsteps) {
      const int k3 = (s + 3) * 32;
      ay0 = *reinterpret_cast<const float4*>(Ap + k3);
      ay1 = *reinterpret_cast<const float4*>(Ap + rowOff + k3);
      wy0 = *reinterpret_cast<const float4*>(Wp + k3);
      wy1 = *reinterpret_cast<const float4*>(Wp + rowOff + k3);
    }
    {
      bf16x8 aF[4], bF[4];
#pragma unroll
      for (int t = 0; t < 4; ++t) {
        aF[t] = *reinterpret_cast<const bf16x8*>(&As[1][wm * 64 + t * 16 + m16][quad * 8]);
        bF[t] = *reinterpret_cast<const bf16x8*>(&Ws[1][wn * 64 + t * 16 + m16][quad * 8]);
      }
#pragma unroll
      for (int mt = 0; mt < 4; ++mt)
#pragma unroll
        for (int nt = 0; nt < 4; ++nt)
          acc[mt][nt] = __builtin_amdgcn_mfma_f32_16x16x32_bf16(aF[mt], bF[nt], acc[mt][nt], 0, 0, 0);
    }
  }
  const int fl = (epi == 3) ? *flagp : 0;
  // C/D layout: col = lane&15, row = quad*4 + reg
#pragma unroll
  for (int mt = 0; mt < 4; ++mt) {
#pragma unroll
    for (int nt = 0; nt < 4; ++nt) {
      const int col = n0 + wn * 64 + nt * 16 + m16;
      const float bv = bf2f(bias[col]);
#pragma unroll
      for (int r = 0; r < 4; ++r) {
        const int row = m0 + wm * 64 + mt * 16 + quad * 4 + r;
        const size_t idx = (size_t)row * N + col;
        float v = acc[mt][nt][r] + bv;
        if (epi == 0) {
          outB[idx] = f2bf(v);
        } else if (epi == 1) {
          outB[idx] = f2bf(0.5f * v * (1.0f + erff(v * 0.70710678118654752f)));
        } else if (epi == 2) {
          residOut[idx] = residIn[idx] + v;
        } else {
          const float rr = residIn[idx] + v;
          if (fl) outF[idx] = rr; else outB[idx] = f2bf(rr);
        }
      }
    }
  }
}

// ---------------- RoPE in-place on qkv buffer [4096, 3072] ----------------
__global__ __launch_bounds__(256) void rope_kernel(bf16* __restrict__ qkv,
                                                   const bf16* __restrict__ cosb,
                                                   const bf16* __restrict__ sinb) {
  const int idx = blockIdx.x * 256 + threadIdx.x;  // over 4096*16*32
  const int i = idx & 31;
  const int h = (idx >> 5) & 15;
  const int r = idx >> 9;
  const int s = r & (Ssz - 1);
  const float c = bf2f(cosb[s * 32 + i]);
  const float sn = bf2f(sinb[s * 32 + i]);
  bf16* base = qkv + (size_t)r * (3 * Dm) + h * 64 + 2 * i;
  float x0 = bf2f(base[0]), x1 = bf2f(base[1]);
  base[0] = f2bf(x0 * c - x1 * sn);
  base[1] = f2bf(x0 * sn + x1 * c);
  x0 = bf2f(base[Dm]); x1 = bf2f(base[Dm + 1]);
  base[Dm] = f2bf(x0 * c - x1 * sn);
  base[Dm + 1] = f2bf(x0 * sn + x1 * c);
}

// ---------------- MFMA flash attention (round-3 verified) ----------------
__global__ __launch_bounds__(256) void attn_mfma(
    const bf16* __restrict__ Qb, const bf16* __restrict__ Kb, const bf16* __restrict__ Vb,
    bf16* __restrict__ Ob, int qStride, int kvStride, int kvLen, int causal, float scale) {
  __shared__ bf16 Ks[64][72];
  __shared__ bf16 Vt[64][72];
  __shared__ bf16 Ps[64][72];
  const int tid = threadIdx.x;
  const int wave = tid >> 6, lane = tid & 63;
  const int quad = lane >> 4, m16 = lane & 15;
  const int b = blockIdx.z, h = blockIdx.y;
  const int q0 = blockIdx.x * 64;
  const int sr = tid >> 2, sc = (tid & 3) * 16;

  {
    const bf16* qp = Qb + (size_t)(b * Ssz + q0 + sr) * qStride + h * 64 + sc;
    float4 a = reinterpret_cast<const float4*>(qp)[0];
    float4 bb2 = reinterpret_cast<const float4*>(qp)[1];
    *reinterpret_cast<float4*>(&Ps[sr][sc]) = a;
    *reinterpret_cast<float4*>(&Ps[sr][sc + 8]) = bb2;
  }
  __syncthreads();
  bf16x8 qf[2];
  qf[0] = *reinterpret_cast<const bf16x8*>(&Ps[wave * 16 + m16][quad * 8]);
  qf[1] = *reinterpret_cast<const bf16x8*>(&Ps[wave * 16 + m16][32 + quad * 8]);

  f32x4 oacc[4] = {};
  float mrow[4], lrow[4];
#pragma unroll
  for (int r = 0; r < 4; ++r) { mrow[r] = -30000.0f; lrow[r] = 0.0f; }

  const int nk = causal ? (q0 + 64) : kvLen;
  for (int kt = 0; kt < nk; kt += 64) {
    {
      const bf16* kp = Kb + (size_t)(b * kvLen + kt + sr) * kvStride + h * 64 + sc;
      float4 k1 = reinterpret_cast<const float4*>(kp)[0];
      float4 k2 = reinterpret_cast<const float4*>(kp)[1];
      *reinterpret_cast<float4*>(&Ks[sr][sc]) = k1;
      *reinterpret_cast<float4*>(&Ks[sr][sc + 8]) = k2;
      const bf16* vp = Vb + (size_t)(b * kvLen + kt + sr) * kvStride + h * 64 + sc;
      float4 v1 = reinterpret_cast<const float4*>(vp)[0];
      float4 v2 = reinterpret_cast<const float4*>(vp)[1];
      const bf16* tv1 = reinterpret_cast<const bf16*>(&v1);
      const bf16* tv2 = reinterpret_cast<const bf16*>(&v2);
#pragma unroll
      for (int j = 0; j < 8; ++j) {
        Vt[sc + j][sr] = tv1[j];
        Vt[sc + 8 + j][sr] = tv2[j];
      }
    }
    __syncthreads();

    f32x4 sacc[4] = {};
#pragma unroll
    for (int nt = 0; nt < 4; ++nt) {
      bf16x8 kf0 = *reinterpret_cast<const bf16x8*>(&Ks[nt * 16 + m16][quad * 8]);
      bf16x8 kf1 = *reinterpret_cast<const bf16x8*>(&Ks[nt * 16 + m16][32 + quad * 8]);
      sacc[nt] = __builtin_amdgcn_mfma_f32_16x16x32_bf16(qf[0], kf0, sacc[nt], 0, 0, 0);
      sacc[nt] = __builtin_amdgcn_mfma_f32_16x16x32_bf16(qf[1], kf1, sacc[nt], 0, 0, 0);
    }
    const bool dmask = (causal != 0) && (kt == q0);
#pragma unroll
    for (int nt = 0; nt < 4; ++nt) {
#pragma unroll
      for (int r = 0; r < 4; ++r) {
        float s = sacc[nt][r] * scale;
        if (dmask && (nt * 16 + m16 > wave * 16 + quad * 4 + r)) s = -30000.0f;
        sacc[nt][r] = s;
      }
    }

#pragma unroll
    for (int r = 0; r < 4; ++r) {
      float mx = fmaxf(fmaxf(sacc[0][r], sacc[1][r]), fmaxf(sacc[2][r], sacc[3][r]));
#pragma unroll
      for (int off = 1; off < 16; off <<= 1) mx = fmaxf(mx, __shfl_xor(mx, off));
      const float mn = fmaxf(mrow[r], mx);
      const float corr = __expf(mrow[r] - mn);
      mrow[r] = mn;
      float psum = 0.0f;
#pragma unroll
      for (int nt = 0; nt < 4; ++nt) {
        const float p = __expf(sacc[nt][r] - mn);
        sacc[nt][r] = p;
        psum += p;
      }
#pragma unroll
      for (int off = 1; off < 16; off <<= 1) psum += __shfl_xor(psum, off);
      lrow[r] = lrow[r] * corr + psum;
#pragma unroll
      for (int nt = 0; nt < 4; ++nt) oacc[nt][r] *= corr;
#pragma unroll
      for (int nt = 0; nt < 4; ++nt)
        Ps[wave * 16 + quad * 4 + r][nt * 16 + m16] = f2bf(sacc[nt][r]);
    }
    bf16x8 pf0 = *reinterpret_cast<const bf16x8*>(&Ps[wave * 16 + m16][quad * 8]);
    bf16x8 pf1 = *reinterpret_cast<const bf16x8*>(&Ps[wave * 16 + m16][32 + quad * 8]);
#pragma unroll
    for (int nt = 0; nt < 4; ++nt) {
      bf16x8 vf0 = *reinterpret_cast<const bf16x8*>(&Vt[nt * 16 + m16][quad * 8]);
      bf16x8 vf1 = *reinterpret_cast<const bf16x8*>(&Vt[nt * 16 + m16][32 + quad * 8]);
      oacc[nt] = __builtin_amdgcn_mfma_f32_16x16x32_bf16(pf0, vf0, oacc[nt], 0, 0, 0);
      oacc[nt] = __builtin_amdgcn_mfma_f32_16x16x32_bf16(pf1, vf1, oacc[nt], 0, 0, 0);
    }
    __syncthreads();
  }

  float inv[4];
#pragma unroll
  for (int r = 0; r < 4; ++r) inv[r] = 1.0f / lrow[r];
#pragma unroll
  for (int r = 0; r < 4; ++r) {
    bf16* op = Ob + (size_t)(b * Ssz + q0 + wave * 16 + quad * 4 + r) * Dm + h * 64 + m16;
#pragma unroll
    for (int nt = 0; nt < 4; ++nt) op[nt * 16] = f2bf(oacc[nt][r] * inv[r]);
  }
}

extern "C" void kernel_launch(void* const* d_in, const int* in_sizes, int n_in,
                              void* d_out, int out_size, void* d_ws, size_t ws_size,
                              hipStream_t stream) {
  char* ws = (char*)d_ws;
  int* flagp   = (int*)ws;                          // [0,1MB) control
  float* resid = (float*)(ws + (1ull << 20));       // 16MB fp32 residual
  bf16* xln    = (bf16*)(ws + (17ull << 20));       // 8MB LN output
  bf16* aout   = (bf16*)(ws + (25ull << 20));       // 8MB attn out
  bf16* big    = (bf16*)(ws + (33ull << 20));       // 32MB: qkv | qb | ffn1
  size_t off   = (65ull << 20);                     // canonical bf16 inputs

  detect_kernel<<<1, 64, 0, stream>>>((const unsigned*)d_in[3], flagp);

  CanonArgs ca;
  bf16* c[23];
  for (int i = 0; i < 23; ++i) {
    if (i == 2) { c[i] = nullptr; ca.src[i] = d_in[i]; ca.dst[i] = nullptr; ca.n[i] = 0; continue; }
    c[i] = (bf16*)(ws + off);
    const int n = in_sizes[i];
    off += ((size_t)n * 2 + 255) & ~(size_t)255;
    ca.src[i] = d_in[i];
    ca.dst[i] = c[i];
    ca.n[i] = n;
  }
  canon_all<<<dim3(256, 23), 256, 0, stream>>>(ca, resid, flagp);

  const bf16 *memory = c[1], *rope_cos = c[3], *rope_sin = c[4];
  const bf16 *qkv_w = c[5], *qkv_b = c[6], *out_w = c[7], *out_b = c[8];
  const bf16 *ca_in_w = c[9], *ca_in_b = c[10], *ca_out_w = c[11], *ca_out_b = c[12];
  const bf16 *ffn_w1 = c[13], *ffn_b1 = c[14], *ffn_w2 = c[15], *ffn_b2 = c[16];
  const bf16 *ln1_g = c[17], *ln1_b = c[18], *ln2_g = c[19], *ln2_b = c[20];
  const bf16 *ln3_g = c[21], *ln3_b = c[22];

  bf16* qb = big;
  bf16* kb = (bf16*)(ws + (41ull << 20));
  bf16* vb = (bf16*)(ws + (43ull << 20));
  bf16* outB = (bf16*)d_out;
  float* outF = (float*)d_out;

  const int ROWS = Bn * Ssz;   // 4096
  const float scale = 0.125f;  // 1/sqrt(64)

  // ---- self attention ----
  ln_kernel<<<ROWS, 256, 0, stream>>>(resid, ln1_g, ln1_b, xln);
  gemm128<<<dim3(ROWS / 128, (3 * Dm) / 128), 256, 0, stream>>>(
      xln, qkv_w, qkv_b, big, nullptr, nullptr, nullptr, nullptr, ROWS, 3 * Dm, Dm, 0);
  rope_kernel<<<(ROWS * Hh * (HDd / 2)) / 256, 256, 0, stream>>>(big, rope_cos, rope_sin);
  attn_mfma<<<dim3(Ssz / 64, Hh, Bn), 256, 0, stream>>>(
      big, big + Dm, big + 2 * Dm, aout, 3 * Dm, 3 * Dm, Ssz, 1, scale);
  gemm128<<<dim3(ROWS / 128, Dm / 128), 256, 0, stream>>>(
      aout, out_w, out_b, nullptr, nullptr, resid, resid, nullptr, ROWS, Dm, Dm, 2);

  // ---- cross attention ----
  ln_kernel<<<ROWS, 256, 0, stream>>>(resid, ln2_g, ln2_b, xln);
  gemm128<<<dim3(ROWS / 128, Dm / 128), 256, 0, stream>>>(
      xln, ca_in_w, ca_in_b, qb, nullptr, nullptr, nullptr, nullptr, ROWS, Dm, Dm, 0);
  gemm_bt<<<dim3((Bn * MEMn) / 64, Dm / 64), 256, 0, stream>>>(
      memory, ca_in_w + (size_t)Dm * Dm, ca_in_b + Dm, kb, nullptr, nullptr, nullptr, nullptr,
      Bn * MEMn, Dm, Dm, 0);
  gemm_bt<<<dim3((Bn * MEMn) / 64, Dm / 64), 256, 0, stream>>>(
      memory, ca_in_w + (size_t)2 * Dm * Dm, ca_in_b + 2 * Dm, vb, nullptr, nullptr, nullptr, nullptr,
      Bn * MEMn, Dm, Dm, 0);
  attn_mfma<<<dim3(Ssz / 64, Hh, Bn), 256, 0, stream>>>(
      qb, kb, vb, aout, Dm, Dm, MEMn, 0, scale);
  gemm128<<<dim3(ROWS / 128, Dm / 128), 256, 0, stream>>>(
      aout, ca_out_w, ca_out_b, nullptr, nullptr, resid, resid, nullptr, ROWS, Dm, Dm, 2);

  // ---- FFN ----
  ln_kernel<<<ROWS, 256, 0, stream>>>(resid, ln3_g, ln3_b, xln);
  gemm128<<<dim3(ROWS / 128, DFFn / 128), 256, 0, stream>>>(
      xln, ffn_w1, ffn_b1, big, nullptr, nullptr, nullptr, nullptr, ROWS, DFFn, Dm, 1);
  gemm128<<<dim3(ROWS / 128, Dm / 128), 256, 0, stream>>>(
      big, ffn_w2, ffn_b2, outB, outF, resid, nullptr, flagp, ROWS, Dm, DFFn, 3);
}